// Round 1
// 945.632 us; speedup vs baseline: 1.4534x; 1.4534x over previous
//
#include <hip/hip_runtime.h>

// RecurrentActorCritic B=512,T=512,S=64,H=128,A=8 (fp32 I/O).
// R11: p1 rewritten as MFMA GEMM. Old p1 was LDS-broadcast-bound: 8x
// ds_read_b128 broadcast per t per thread = 3072 b128-instr/round/CU
// (~37K cyc) -> ~490us of pure LDS pipe. New p1: 4096 blocks x 256thr,
// 64 rows each: stage x fp16 -> mfma_f32_16x16x32_f16 GEMM1 (N=128,
// 4 waves x 32) -> f32 LN/ReLU (4 thr/row, shfl_xor) -> GEMM2 transposed
// (A=Wih rows, B=z^T) so C/D layout packs 4 consecutive gx cols/lane ->
// 8B stores. A/B frags loaded with identical k-bijection (hi*8+reg) on
// both operands => HW k-permutation cancels; only C/D mapping
// (col=lane&15,row=(lane>>4)*4+reg, measured) must hold.
// p2 byte-identical to R10 (2 chains/block phase-offset, 727us).

typedef _Float16 h2t __attribute__((ext_vector_type(2)));
typedef float f16v __attribute__((ext_vector_type(16)));
typedef _Float16 f16x8 __attribute__((ext_vector_type(8)));
typedef float f32x4 __attribute__((ext_vector_type(4)));

__device__ __forceinline__ float dot2a(h2t a, h2t b, float c) {
    return __builtin_amdgcn_fdot2(a, b, c, false);
}
__device__ __forceinline__ h2t f2h(float f) { return __builtin_bit_cast(h2t, f); }
__device__ __forceinline__ float pk2(float lo, float hi) {
    h2t a; a.x = (_Float16)lo; a.y = (_Float16)hi;
    return __builtin_bit_cast(float, a);
}
__device__ __forceinline__ unsigned short hpk(float v) {
    return __builtin_bit_cast(unsigned short, (_Float16)v);
}

// LDS-only barrier: drain ds ops, leave global loads/stores in flight.
#define BAR() __asm__ volatile("s_waitcnt lgkmcnt(0)\n\ts_barrier" ::: "memory")

#define BB 512
#define TT 512
#define SS 64
#define HH 128
#define AA 8
#define CK 16
#define NCK (TT / CK)
#define VALO (BB * TT * AA)
#define HFIN (VALO + BB * TT)

#define LDW16(WV, P2, OFS) { float2 v_; \
    v_=(P2)[(OFS)+0];  WV[0] =pk2(v_.x,v_.y); v_=(P2)[(OFS)+1];  WV[1] =pk2(v_.x,v_.y); \
    v_=(P2)[(OFS)+2];  WV[2] =pk2(v_.x,v_.y); v_=(P2)[(OFS)+3];  WV[3] =pk2(v_.x,v_.y); \
    v_=(P2)[(OFS)+4];  WV[4] =pk2(v_.x,v_.y); v_=(P2)[(OFS)+5];  WV[5] =pk2(v_.x,v_.y); \
    v_=(P2)[(OFS)+6];  WV[6] =pk2(v_.x,v_.y); v_=(P2)[(OFS)+7];  WV[7] =pk2(v_.x,v_.y); \
    v_=(P2)[(OFS)+8];  WV[8] =pk2(v_.x,v_.y); v_=(P2)[(OFS)+9];  WV[9] =pk2(v_.x,v_.y); \
    v_=(P2)[(OFS)+10]; WV[10]=pk2(v_.x,v_.y); v_=(P2)[(OFS)+11]; WV[11]=pk2(v_.x,v_.y); \
    v_=(P2)[(OFS)+12]; WV[12]=pk2(v_.x,v_.y); v_=(P2)[(OFS)+13]; WV[13]=pk2(v_.x,v_.y); \
    v_=(P2)[(OFS)+14]; WV[14]=pk2(v_.x,v_.y); v_=(P2)[(OFS)+15]; WV[15]=pk2(v_.x,v_.y); }

// half-row (w0,w1 = 32 pairs) dot LDS half-vector at ph4 (8 float4) -> A0
#define HMVX(A0) { float4 u_; float c0_=0.f,c1_=0.f,c2_=0.f,c3_=0.f; \
  u_=ph4[0]; c0_=dot2a(f2h(w0[0]), f2h(u_.x),c0_); c0_=dot2a(f2h(w0[1]), f2h(u_.y),c0_); c0_=dot2a(f2h(w0[2]), f2h(u_.z),c0_); c0_=dot2a(f2h(w0[3]), f2h(u_.w),c0_); \
  u_=ph4[1]; c1_=dot2a(f2h(w0[4]), f2h(u_.x),c1_); c1_=dot2a(f2h(w0[5]), f2h(u_.y),c1_); c1_=dot2a(f2h(w0[6]), f2h(u_.z),c1_); c1_=dot2a(f2h(w0[7]), f2h(u_.w),c1_); \
  u_=ph4[2]; c2_=dot2a(f2h(w0[8]), f2h(u_.x),c2_); c2_=dot2a(f2h(w0[9]), f2h(u_.y),c2_); c2_=dot2a(f2h(w0[10]),f2h(u_.z),c2_); c2_=dot2a(f2h(w0[11]),f2h(u_.w),c2_); \
  u_=ph4[3]; c3_=dot2a(f2h(w0[12]),f2h(u_.x),c3_); c3_=dot2a(f2h(w0[13]),f2h(u_.y),c3_); c3_=dot2a(f2h(w0[14]),f2h(u_.z),c3_); c3_=dot2a(f2h(w0[15]),f2h(u_.w),c3_); \
  u_=ph4[4]; c0_=dot2a(f2h(w1[0]), f2h(u_.x),c0_); c0_=dot2a(f2h(w1[1]), f2h(u_.y),c0_); c0_=dot2a(f2h(w1[2]), f2h(u_.z),c0_); c0_=dot2a(f2h(w1[3]), f2h(u_.w),c0_); \
  u_=ph4[5]; c1_=dot2a(f2h(w1[4]), f2h(u_.x),c1_); c1_=dot2a(f2h(w1[5]), f2h(u_.y),c1_); c1_=dot2a(f2h(w1[6]), f2h(u_.z),c1_); c1_=dot2a(f2h(w1[7]), f2h(u_.w),c1_); \
  u_=ph4[6]; c2_=dot2a(f2h(w1[8]), f2h(u_.x),c2_); c2_=dot2a(f2h(w1[9]), f2h(u_.y),c2_); c2_=dot2a(f2h(w1[10]),f2h(u_.z),c2_); c2_=dot2a(f2h(w1[11]),f2h(u_.w),c2_); \
  u_=ph4[7]; c3_=dot2a(f2h(w1[12]),f2h(u_.x),c3_); c3_=dot2a(f2h(w1[13]),f2h(u_.y),c3_); c3_=dot2a(f2h(w1[14]),f2h(u_.z),c3_); c3_=dot2a(f2h(w1[15]),f2h(u_.w),c3_); \
  A0 = (c0_ + c1_) + (c2_ + c3_); }

// ======================= PHASE 1 (MFMA rewrite) =======================
// 4096 blocks x 256 threads; 64 rows (one b,t-tile) per block.
__global__ void __launch_bounds__(256, 2) p1_kernel(
    const float* __restrict__ x,   const float* __restrict__ Wf,
    const float* __restrict__ bfe, const float* __restrict__ gf,
    const float* __restrict__ btf, const float* __restrict__ Wih,
    const float* __restrict__ bih, unsigned short* __restrict__ gxws)
{
    const int tid = threadIdx.x;
    const int wv  = tid >> 6;
    const int l   = tid & 63;
    const int lo  = l & 15;
    const int hi  = l >> 4;
    const size_t m0 = (size_t)blockIdx.x * 64;

    __shared__ __align__(16) _Float16 xh[64][72];    //  9.2 KB (pad: 2-way max)
    __shared__ __align__(16) float    fb[64][132];   // 33.8 KB
    __shared__ __align__(16) _Float16 zh[64][136];   // 17.4 KB

    // ---- stage x tile: 64 rows x 64 f32 -> fp16 LDS ----
    {
        const int r  = tid >> 2;
        const int c0 = (tid & 3) << 4;
        const float4* px = (const float4*)(x + (m0 + (size_t)r) * SS + c0);
        float4 a = px[0], b = px[1], c = px[2], d = px[3];
        f16x8 h0, h1;
        h0[0]=(_Float16)a.x; h0[1]=(_Float16)a.y; h0[2]=(_Float16)a.z; h0[3]=(_Float16)a.w;
        h0[4]=(_Float16)b.x; h0[5]=(_Float16)b.y; h0[6]=(_Float16)b.z; h0[7]=(_Float16)b.w;
        h1[0]=(_Float16)c.x; h1[1]=(_Float16)c.y; h1[2]=(_Float16)c.z; h1[3]=(_Float16)c.w;
        h1[4]=(_Float16)d.x; h1[5]=(_Float16)d.y; h1[6]=(_Float16)d.z; h1[7]=(_Float16)d.w;
        *(f16x8*)&xh[r][c0]     = h0;
        *(f16x8*)&xh[r][c0 + 8] = h1;
    }
    __syncthreads();

    // ---- GEMM1: fb = x @ Wf^T + bfe  (M=64, N=128 = 4 waves x 32, K=64) ----
    {
        const int n0 = wv << 5;
        f32x4 acc[4][2];
        #pragma unroll
        for (int mt = 0; mt < 4; ++mt)
            #pragma unroll
            for (int nt = 0; nt < 2; ++nt) {
                acc[mt][nt][0]=0.f; acc[mt][nt][1]=0.f;
                acc[mt][nt][2]=0.f; acc[mt][nt][3]=0.f;
            }
        #pragma unroll
        for (int kk = 0; kk < 2; ++kk) {
            f16x8 bf[2];
            #pragma unroll
            for (int nt = 0; nt < 2; ++nt) {
                const float4* wp = (const float4*)(Wf + (size_t)(n0 + nt*16 + lo) * SS + kk*32 + hi*8);
                float4 w0 = wp[0], w1 = wp[1];
                f16x8 t;
                t[0]=(_Float16)w0.x; t[1]=(_Float16)w0.y; t[2]=(_Float16)w0.z; t[3]=(_Float16)w0.w;
                t[4]=(_Float16)w1.x; t[5]=(_Float16)w1.y; t[6]=(_Float16)w1.z; t[7]=(_Float16)w1.w;
                bf[nt] = t;
            }
            #pragma unroll
            for (int mt = 0; mt < 4; ++mt) {
                f16x8 af = *(const f16x8*)&xh[mt*16 + lo][kk*32 + hi*8];
                acc[mt][0] = __builtin_amdgcn_mfma_f32_16x16x32_f16(af, bf[0], acc[mt][0], 0, 0, 0);
                acc[mt][1] = __builtin_amdgcn_mfma_f32_16x16x32_f16(af, bf[1], acc[mt][1], 0, 0, 0);
            }
        }
        const float b0 = bfe[n0 + lo];
        const float b1 = bfe[n0 + 16 + lo];
        #pragma unroll
        for (int mt = 0; mt < 4; ++mt)
            #pragma unroll
            for (int j = 0; j < 4; ++j) {
                fb[mt*16 + hi*4 + j][n0 + lo]      = acc[mt][0][j] + b0;
                fb[mt*16 + hi*4 + j][n0 + 16 + lo] = acc[mt][1][j] + b1;
            }
    }
    __syncthreads();

    // ---- LN + ReLU -> zh fp16  (4 threads per row, shfl_xor combine) ----
    {
        const int r = tid >> 2;
        const int q = tid & 3;
        const float4* pf = (const float4*)&fb[r][q << 5];
        float4 v[8];
        float s = 0.f, ss = 0.f;
        #pragma unroll
        for (int i = 0; i < 8; ++i) {
            float4 t = pf[i]; v[i] = t;
            s  += (t.x + t.y) + (t.z + t.w);
            ss += (t.x*t.x + t.y*t.y) + (t.z*t.z + t.w*t.w);
        }
        s  += __shfl_xor(s, 1);  s  += __shfl_xor(s, 2);
        ss += __shfl_xor(ss, 1); ss += __shfl_xor(ss, 2);
        const float mu   = s * (1.f / 128.f);
        const float rstd = rsqrtf(ss * (1.f / 128.f) - mu * mu + 1e-5f);
        const float4* pg = (const float4*)(gf  + (q << 5));
        const float4* pb = (const float4*)(btf + (q << 5));
        #pragma unroll
        for (int i = 0; i < 8; ++i) {
            float4 g = pg[i], bb = pb[i], t = v[i];
            h2t pA, pB;
            pA.x = (_Float16)fmaxf((t.x - mu) * rstd * g.x + bb.x, 0.f);
            pA.y = (_Float16)fmaxf((t.y - mu) * rstd * g.y + bb.y, 0.f);
            pB.x = (_Float16)fmaxf((t.z - mu) * rstd * g.z + bb.z, 0.f);
            pB.y = (_Float16)fmaxf((t.w - mu) * rstd * g.w + bb.w, 0.f);
            uint2 u;
            u.x = __builtin_bit_cast(unsigned int, pA);
            u.y = __builtin_bit_cast(unsigned int, pB);
            *(uint2*)&zh[r][(q << 5) + i * 4] = u;
        }
    }
    __syncthreads();

    // ---- GEMM2 (transposed): D[n][m] = sum_k Wih[n][k] z[m][k], N=384 = 4 waves x 96 ----
    // A = Wih rows (row-in-tile = lo), B = z^T (col-in-tile = lo -> m).
    // C/D: row n = hi*4+j, col m = lo  => 4 consecutive gx columns per lane -> 8B store.
    {
        const int n0 = wv * 96;
        f16x8 bz[4][4];
        #pragma unroll
        for (int mt = 0; mt < 4; ++mt)
            #pragma unroll
            for (int ks = 0; ks < 4; ++ks)
                bz[mt][ks] = *(const f16x8*)&zh[mt*16 + lo][ks*32 + hi*8];
        #pragma unroll
        for (int nt = 0; nt < 6; ++nt) {
            const int nb = n0 + nt * 16;
            const float4 b4 = *(const float4*)(bih + nb + (hi << 2));
            const float* wr = Wih + (size_t)(nb + lo) * HH;
            f32x4 acc[4];
            #pragma unroll
            for (int mt = 0; mt < 4; ++mt) {
                acc[mt][0]=0.f; acc[mt][1]=0.f; acc[mt][2]=0.f; acc[mt][3]=0.f;
            }
            #pragma unroll
            for (int ks = 0; ks < 4; ++ks) {
                const float4* wp = (const float4*)(wr + ks*32 + hi*8);
                float4 w0 = wp[0], w1 = wp[1];
                f16x8 af;
                af[0]=(_Float16)w0.x; af[1]=(_Float16)w0.y; af[2]=(_Float16)w0.z; af[3]=(_Float16)w0.w;
                af[4]=(_Float16)w1.x; af[5]=(_Float16)w1.y; af[6]=(_Float16)w1.z; af[7]=(_Float16)w1.w;
                #pragma unroll
                for (int mt = 0; mt < 4; ++mt)
                    acc[mt] = __builtin_amdgcn_mfma_f32_16x16x32_f16(af, bz[mt][ks], acc[mt], 0, 0, 0);
            }
            #pragma unroll
            for (int mt = 0; mt < 4; ++mt) {
                h2t pA, pB;
                pA.x = (_Float16)(acc[mt][0] + b4.x);
                pA.y = (_Float16)(acc[mt][1] + b4.y);
                pB.x = (_Float16)(acc[mt][2] + b4.z);
                pB.y = (_Float16)(acc[mt][3] + b4.w);
                uint2 u;
                u.x = __builtin_bit_cast(unsigned int, pA);
                u.y = __builtin_bit_cast(unsigned int, pB);
                *(uint2*)(gxws + (m0 + (size_t)(mt*16 + lo)) * 384 + nb + (hi << 2)) = u;
            }
        }
    }
}

// ======================= PHASE 2 =======================
// 256 blocks, 2 chains each (bA=2*blk, bB=2*blk+1), phase-offset intervals.
__global__ void __launch_bounds__(768, 2) p2_kernel(
    const float* __restrict__ hx,  const int* __restrict__ done,
    const float* __restrict__ Whh, const float* __restrict__ bhh,
    const float* __restrict__ gr,  const float* __restrict__ btr,
    const float* __restrict__ Wp,  const float* __restrict__ bp,
    const float* __restrict__ Wv,  const float* __restrict__ bv,
    const unsigned short* __restrict__ gxws, float* __restrict__ out)
{
    const int tid = threadIdx.x;
    const int blk = blockIdx.x;

    __shared__ __align__(16) _Float16 hsh[2][HH];
    __shared__ __align__(16) float ghl[2][384];
    __shared__ __align__(16) _Float16 gxb[2][2][CK][384];   // 48 KB
    __shared__ __align__(16) float hnr[2][32][132];          // 33.8 KB
    __shared__ __align__(16) float ylr[2][CK][132];          // 16.9 KB
    __shared__ __align__(16) float wpl[9][132];
    __shared__ float bpl[9];
    __shared__ __align__(16) float grl[HH], btrl[HH];
    __shared__ float musd[2][CK][2];
    __shared__ int dsh[2][TT];

    const int l  = tid & 63;
    const int w  = tid >> 6;
    const int r  = (w << 5) | (l & 31);
    const int hf = (l >> 5) & 1;

    f16v w0, w1;   // half Whh row (shared by both chains)
    {
        const float2* p2 = (const float2*)(Whh + r * HH + hf * 64);
        LDW16(w0, p2, 0) LDW16(w1, p2, 16)
    }
    const float breg = bhh[r];

    float hprevA = 0.f, hprevB = 0.f;
    if (tid < HH) {
        hprevA = hx[(2 * blk + 0) * HH + tid];
        hprevB = hx[(2 * blk + 1) * HH + tid];
        hsh[0][tid] = (_Float16)hprevA;
        hsh[1][tid] = (_Float16)hprevB;
        grl[tid] = gr[tid]; btrl[tid] = btr[tid];
    }
    for (int idx = tid; idx < 9 * HH; idx += 768) {
        int row = idx >> 7, col = idx & 127;
        wpl[row][col] = (row < 8) ? Wp[row * HH + col] : Wv[col];
    }
    if (tid < 9) bpl[tid] = (tid < 8) ? bp[tid] : bv[0];
    for (int idx = tid; idx < 2 * TT; idx += 768)
        dsh[idx >> 9][idx & 511] = done[(2 * blk + (idx >> 9)) * TT + (idx & 511)];

    // gx staging: threads 128-383 (256), 6 ushort4 per chain per chunk
    const bool isStg = (tid >= 128) && (tid < 384);
    const int  sSt = tid - 128;
    const unsigned short* baseA = gxws + (size_t)(2 * blk + 0) * TT * 384;
    const unsigned short* baseB = gxws + (size_t)(2 * blk + 1) * TT * 384;
    ushort4 rA0, rA1, rA2, rA3, rA4, rA5, rB0, rB1, rB2, rB3, rB4, rB5;
    if (isStg) {   // chunk 0 -> buffer 0
        const ushort4* ca = (const ushort4*)baseA;
        const ushort4* cbp = (const ushort4*)baseB;
        rA0=ca[0*256+sSt]; rA1=ca[1*256+sSt]; rA2=ca[2*256+sSt];
        rA3=ca[3*256+sSt]; rA4=ca[4*256+sSt]; rA5=ca[5*256+sSt];
        rB0=cbp[0*256+sSt]; rB1=cbp[1*256+sSt]; rB2=cbp[2*256+sSt];
        rB3=cbp[3*256+sSt]; rB4=cbp[4*256+sSt]; rB5=cbp[5*256+sSt];
        ushort4* ga = (ushort4*)&gxb[0][0][0][0];
        ushort4* gb = (ushort4*)&gxb[1][0][0][0];
        ga[0*256+sSt]=rA0; ga[1*256+sSt]=rA1; ga[2*256+sSt]=rA2;
        ga[3*256+sSt]=rA3; ga[4*256+sSt]=rA4; ga[5*256+sSt]=rA5;
        gb[0*256+sSt]=rB0; gb[1*256+sSt]=rB1; gb[2*256+sSt]=rB2;
        gb[3*256+sSt]=rB3; gb[4*256+sSt]=rB4; gb[5*256+sSt]=rB5;
    }
    __syncthreads();

    const int s2 = tid - 512;   // burst lane (tid >= 512)

    // ---- gate step (tid < 128, d = tid) ----
    #define GATES(Y, T, HPREV) { \
        int d_ = tid; int sb_ = ((T) >> 4) & 1, sj_ = (T) & 15; \
        const _Float16* gxv = gxb[Y][sb_][sj_]; \
        const float* gy = ghl[Y]; \
        float xr_ = (float)gxv[d_] + gy[d_]; \
        float xz_ = (float)gxv[128 + d_] + gy[128 + d_]; \
        float xn_ = (float)gxv[256 + d_]; \
        float hn_ = gy[256 + d_]; \
        float r_ = 1.f / (1.f + __expf(-xr_)); \
        float u_ = 1.f / (1.f + __expf(-xz_)); \
        float a_ = xn_ + r_ * hn_; \
        a_ = fminf(fmaxf(a_, -20.f), 20.f); \
        float e2_ = __expf(2.f * a_); \
        float n_ = (e2_ - 1.f) / (e2_ + 1.f); \
        float hn2_ = (1.f - u_) * n_ + u_ * HPREV; \
        hnr[Y][(T) & 31][d_] = hn2_; \
        float hm_ = hn2_ * (dsh[Y][T] ? 0.f : 1.f); \
        HPREV = hm_; \
        hsh[Y][d_] = (_Float16)hm_; \
        if ((T) == TT - 1) out[HFIN + (2 * blk + (Y)) * HH + d_] = hm_; }

    // ---- bursts for chain Y, chunk cm1 (zero cross-lane) ----
    #define BSTAT(Y, CM1, SL) { \
        int row_ = (((CM1) * CK + (SL)) & 31); \
        const float4* ph_ = (const float4*)hnr[Y][row_]; \
        float sv_ = 0.f, qv_ = 0.f; \
        for (int k2 = 0; k2 < 32; ++k2) { float4 v_ = ph_[k2]; \
            sv_ += (v_.x + v_.y) + (v_.z + v_.w); \
            qv_ += (v_.x*v_.x + v_.y*v_.y) + (v_.z*v_.z + v_.w*v_.w); } \
        float mu_ = sv_ * (1.f / 128.f); \
        musd[Y][SL][0] = mu_; \
        musd[Y][SL][1] = rsqrtf(qv_ * (1.f / 128.f) - mu_ * mu_ + 1e-5f); }

    #define BY(Y, CM1, SL) { \
        int t16_ = (SL) >> 4, k_ = (SL) & 15; \
        int row_ = (((CM1) * CK + t16_) & 31); \
        float mu_ = musd[Y][t16_][0], rs_ = musd[Y][t16_][1]; \
        const float4* ph_ = (const float4*)&hnr[Y][row_][k_ * 8]; \
        const float4* pg_ = (const float4*)&grl[k_ * 8]; \
        const float4* pb_ = (const float4*)&btrl[k_ * 8]; \
        float4 h0_ = ph_[0], h1_ = ph_[1], g0_ = pg_[0], g1_ = pg_[1], b0_ = pb_[0], b1_ = pb_[1]; \
        float4 y0_, y1_; \
        y0_.x = (h0_.x - mu_) * rs_ * g0_.x + b0_.x; \
        y0_.y = (h0_.y - mu_) * rs_ * g0_.y + b0_.y; \
        y0_.z = (h0_.z - mu_) * rs_ * g0_.z + b0_.z; \
        y0_.w = (h0_.w - mu_) * rs_ * g0_.w + b0_.w; \
        y1_.x = (h1_.x - mu_) * rs_ * g1_.x + b1_.x; \
        y1_.y = (h1_.y - mu_) * rs_ * g1_.y + b1_.y; \
        y1_.z = (h1_.z - mu_) * rs_ * g1_.z + b1_.z; \
        y1_.w = (h1_.w - mu_) * rs_ * g1_.w + b1_.w; \
        ((float4*)&ylr[Y][t16_][k_ * 8])[0] = y0_; \
        ((float4*)&ylr[Y][t16_][k_ * 8])[1] = y1_; }

    #define BHEAD(Y, CM1, SL) { \
        int t16_ = (SL) / 9, hd_ = (SL) - t16_ * 9; \
        const float4* py_ = (const float4*)ylr[Y][t16_]; \
        const float4* pw_ = (const float4*)wpl[hd_]; \
        float acc_ = 0.f; \
        for (int k2 = 0; k2 < 32; ++k2) { float4 yv_ = py_[k2], wv_ = pw_[k2]; \
            acc_ += (yv_.x*wv_.x + yv_.y*wv_.y) + (yv_.z*wv_.z + yv_.w*wv_.w); } \
        int t_ = (CM1) * CK + t16_; \
        float o_ = acc_ + bpl[hd_]; \
        if (hd_ < 8) out[((size_t)(2 * blk + (Y)) * TT + t_) * AA + hd_] = o_; \
        else         out[VALO + (2 * blk + (Y)) * TT + t_] = o_; }

    #define MV(Y) { \
        const float4* ph4 = ((const float4*)hsh[Y]) + hf * 8; \
        float a0; HMVX(a0) \
        a0 += __shfl_xor(a0, 32); \
        if (hf == 0) ghl[Y][r] = a0 + breg; }

    for (int c = 0; c < NCK; ++c) {
        if (isStg && c + 1 < NCK) {   // issue next-chunk loads (16-step slack)
            const ushort4* ca = (const ushort4*)(baseA + (size_t)(c + 1) * CK * 384);
            const ushort4* cbp = (const ushort4*)(baseB + (size_t)(c + 1) * CK * 384);
            rA0=ca[0*256+sSt]; rA1=ca[1*256+sSt]; rA2=ca[2*256+sSt];
            rA3=ca[3*256+sSt]; rA4=ca[4*256+sSt]; rA5=ca[5*256+sSt];
            rB0=cbp[0*256+sSt]; rB1=cbp[1*256+sSt]; rB2=cbp[2*256+sSt];
            rB3=cbp[3*256+sSt]; rB4=cbp[4*256+sSt]; rB5=cbp[5*256+sSt];
        }
        for (int j = 0; j < CK; ++j) {
            const int i = c * CK + j;
            // ===== interval alpha: mv_A(i) + gates_B(i-1) + B-bursts =====
            MV(0)
            if (tid < HH && i >= 1) GATES(1, i - 1, hprevB)
            if (tid >= 512 && c >= 1) {
                if (j == 1 && s2 < CK)       BSTAT(1, c - 1, s2)
                else if (j == 2)             BY(1, c - 1, s2)
                else if (j == 3 && s2 < 144) BHEAD(1, c - 1, s2)
            }
            BAR();
            // ===== interval beta: mv_B(i) + gates_A(i) + A-bursts =====
            MV(1)
            if (tid < HH) GATES(0, i, hprevA)
            if (tid >= 512 && c >= 1) {
                if (j == 1 && s2 < CK)       BSTAT(0, c - 1, s2)
                else if (j == 2)             BY(0, c - 1, s2)
                else if (j == 3 && s2 < 144) BHEAD(0, c - 1, s2)
            }
            BAR();
        }
        if (isStg && c + 1 < NCK) {   // write staged regs into buffer (c+1)&1
            const int nb = (c + 1) & 1;
            ushort4* ga = (ushort4*)&gxb[0][nb][0][0];
            ushort4* gb = (ushort4*)&gxb[1][nb][0][0];
            ga[0*256+sSt]=rA0; ga[1*256+sSt]=rA1; ga[2*256+sSt]=rA2;
            ga[3*256+sSt]=rA3; ga[4*256+sSt]=rA4; ga[5*256+sSt]=rA5;
            gb[0*256+sSt]=rB0; gb[1*256+sSt]=rB1; gb[2*256+sSt]=rB2;
            gb[3*256+sSt]=rB3; gb[4*256+sSt]=rB4; gb[5*256+sSt]=rB5;
        }
    }

    // ===== epilogue =====
    if (tid < HH) GATES(1, TT - 1, hprevB)   // gates_B(511)
    BAR();
    if (tid >= 512) {                         // stats chunk 31, both chains
        if (s2 < CK)                    BSTAT(0, NCK - 1, s2)
        else if (s2 < 2 * CK)           BSTAT(1, NCK - 1, s2 - CK)
    }
    BAR();
    if (tid >= 512) BY(0, NCK - 1, s2)
    if (tid >= 256 && tid < 512) { int s3 = tid - 256; BY(1, NCK - 1, s3) }
    BAR();
    if (tid >= 512 && s2 < 144) BHEAD(0, NCK - 1, s2)
    if (tid >= 256 && tid < 400) { int s3 = tid - 256; BHEAD(1, NCK - 1, s3) }
}

extern "C" void kernel_launch(void* const* d_in, const int* in_sizes, int n_in,
                              void* d_out, int out_size, void* d_ws, size_t ws_size,
                              hipStream_t stream) {
    const float* x   = (const float*)d_in[0];
    const float* hx  = (const float*)d_in[1];
    const int*   dn  = (const int*)d_in[2];
    const float* Wf  = (const float*)d_in[3];
    const float* bfe = (const float*)d_in[4];
    const float* gf  = (const float*)d_in[5];
    const float* btf = (const float*)d_in[6];
    const float* Wih = (const float*)d_in[7];
    const float* Whh = (const float*)d_in[8];
    const float* bih = (const float*)d_in[9];
    const float* bhh = (const float*)d_in[10];
    const float* gr  = (const float*)d_in[11];
    const float* btr = (const float*)d_in[12];
    const float* Wp  = (const float*)d_in[13];
    const float* bp  = (const float*)d_in[14];
    const float* Wv  = (const float*)d_in[15];
    const float* bv  = (const float*)d_in[16];
    float* out = (float*)d_out;

    unsigned short* gxws = (unsigned short*)d_ws;   // 201.3 MB gx buffer
    hipLaunchKernelGGL(p1_kernel, dim3(BB * TT / 64), dim3(256), 0, stream,
                       x, Wf, bfe, gf, btf, Wih, bih, gxws);
    hipLaunchKernelGGL(p2_kernel, dim3(BB / 2), dim3(768), 0, stream,
                       hx, dn, Whh, bhh, gr, btr, Wp, bp, Wv, bv, gxws, out);
}